// Round 7
// baseline (340.953 us; speedup 1.0000x reference)
//
#include <hip/hip_runtime.h>
#include <stdint.h>

#define T_SEQ 1024

typedef __attribute__((ext_vector_type(8))) short short8;
typedef __attribute__((ext_vector_type(4))) float f32x4;
typedef __attribute__((ext_vector_type(4))) unsigned short ushort4v;
typedef __attribute__((ext_vector_type(8))) unsigned short ushort8v;

typedef __attribute__((address_space(1))) const unsigned int gu32;
typedef __attribute__((address_space(3))) unsigned int su32;

// async global -> LDS, 16B per lane; LDS dest = uniform base + lane*16
__device__ __forceinline__ void glds16(const unsigned short* g, unsigned short* l) {
  __builtin_amdgcn_global_load_lds((gu32*)g, (su32*)l, 16, 0, 0);
}

__device__ __forceinline__ unsigned short f2bf(float f) {
  union { float f; uint32_t u; } v; v.f = f;
  return (unsigned short)((v.u + 0x7fffu + ((v.u >> 16) & 1u)) >> 16);
}
__device__ __forceinline__ float bf2f(unsigned short u) {
  union { uint32_t u; float f; } v; v.u = ((uint32_t)u) << 16;
  return v.f;
}

// ---------------- threefry2x32, JAX partitionable mode ----------------
__device__ __forceinline__ uint32_t tf_bits(uint32_t flat) {
  const uint32_t ks1 = 42u;
  const uint32_t ks2 = 0x1BD11BDAu ^ 42u;
  uint32_t x0 = 0u;
  uint32_t x1 = flat + ks1;
#define TFR(r) { x0 += x1; x1 = (x1 << (r)) | (x1 >> (32 - (r))); x1 ^= x0; }
  TFR(13) TFR(15) TFR(26) TFR(6)
  x0 += ks1; x1 += ks2 + 1u;
  TFR(17) TFR(29) TFR(16) TFR(24)
  x0 += ks2; x1 += 2u;
  TFR(13) TFR(15) TFR(26) TFR(6)
  x1 += ks1 + 3u;
  TFR(17) TFR(29) TFR(16) TFR(24)
  x0 += ks1; x1 += ks2 + 4u;
  TFR(13) TFR(15) TFR(26) TFR(6)
  x0 += ks2; x1 += 5u;
#undef TFR
  return x0 ^ x1;
}

__device__ __forceinline__ float gumbel_noise(uint32_t flat) {
  const uint32_t bits = tf_bits(flat);
  const float u = __uint_as_float((bits >> 9) | 0x3f800000u) - 1.0f;
  return -__logf(-__logf(u + 1e-20f) + 1e-20f);
}

// ---------------- pre-conversion pass: fp32 -> bf16 (split for activations) ----------------
__global__ __launch_bounds__(256) void convert_pre(
    const float* __restrict__ g, const float* __restrict__ h,
    const float* __restrict__ wgi_f, const float* __restrict__ whi_f,
    const float* __restrict__ wgo_f, const float* __restrict__ who_f,
    unsigned short* __restrict__ ghi, unsigned short* __restrict__ glo,
    unsigned short* __restrict__ hhi, unsigned short* __restrict__ hlo,
    unsigned short* __restrict__ wgi, unsigned short* __restrict__ whi,
    unsigned short* __restrict__ wgo, unsigned short* __restrict__ who)
{
  const int64_t Q_SPLIT = 1048576;
  const int64_t Q_TOTAL = Q_SPLIT + 1835008;
  for (int64_t qd = (int64_t)blockIdx.x * 256 + threadIdx.x; qd < Q_TOTAL;
       qd += (int64_t)gridDim.x * 256) {
    if (qd < Q_SPLIT) {
      const int which = qd >= 524288;
      const int64_t e = (qd - (which ? 524288 : 0)) * 4;
      const float4 v = *(const float4*)((which ? h : g) + e);
      ushort4v hi = {f2bf(v.x), f2bf(v.y), f2bf(v.z), f2bf(v.w)};
      ushort4v lo = {f2bf(v.x - bf2f(hi[0])), f2bf(v.y - bf2f(hi[1])),
                     f2bf(v.z - bf2f(hi[2])), f2bf(v.w - bf2f(hi[3]))};
      *(ushort4v*)((which ? hhi : ghi) + e) = hi;
      *(ushort4v*)((which ? hlo : glo) + e) = lo;
    } else {
      int64_t off = qd - Q_SPLIT;
      const float* src; unsigned short* dst;
      if (off < 786432)                 { src = wgi_f; dst = wgi; }
      else if (off < 1310720)           { off -= 786432;  src = whi_f; dst = whi; }
      else if (off < 1572864)           { off -= 1310720; src = wgo_f; dst = wgo; }
      else                              { off -= 1572864; src = who_f; dst = who; }
      const int64_t e = off * 4;
      const float4 v = *(const float4*)(src + e);
      ushort4v u = {f2bf(v.x), f2bf(v.y), f2bf(v.z), f2bf(v.w)};
      *(ushort4v*)(dst + e) = u;
    }
  }
}

// ---------------- bf16 MFMA GEMM, fragment-major LDS + global_load_lds ----------------
// Tile: (TM*32) rows x 128 cols, BK=64, 256 threads = 4 waves (2x2); wave tile (TM*16)x64.
// LDS tile (rb,kk) holds lane L's 8-element frag at (rb*2+kk)*512 + L*8 shorts:
// element = M[rb*16 + (L&15)][k0 + 32kk + 8*(L>>4) + j]. Frag read = linear ds_read_b128.
template<int TM, bool SPLIT, bool BF16OUT>
__device__ __forceinline__ void gemm_core2(
    const unsigned short* __restrict__ Ahi, const unsigned short* __restrict__ Alo,
    const unsigned short* __restrict__ Wg, const float* __restrict__ bias,
    int N, int K, int m0, int n0, int scale_limit, void* Cout,
    unsigned short* sA, unsigned short* sL, unsigned short* sW)
{
  const int tid = threadIdx.x;
  const int w = tid >> 6;
  const int lane = tid & 63;
  const int txl = lane & 15, q = lane >> 4;
  const int wr = (w >> 1) * (TM * 16);
  const int wc = (w & 1) << 6;
  const int NA = TM * 4;  // A tiles per plane

  f32x4 acc[TM][4];
#pragma unroll
  for (int i = 0; i < TM; i++)
#pragma unroll
    for (int j = 0; j < 4; j++) acc[i][j] = (f32x4){0.f, 0.f, 0.f, 0.f};

  for (int k0 = 0; k0 < K; k0 += 64) {
    __syncthreads();  // previous iter's frag reads complete
#pragma unroll
    for (int t = 0; t < NA / 4; t++) {
      const int a = w * (NA / 4) + t;
      const int rb = a >> 1, kk = a & 1;
      const size_t goff = (size_t)(m0 + rb * 16 + txl) * K + k0 + kk * 32 + 8 * q;
      glds16(Ahi + goff, sA + a * 512);
      if (SPLIT) glds16(Alo + goff, sL + a * 512);
    }
#pragma unroll
    for (int t = 0; t < 4; t++) {
      const int a = w * 4 + t;
      const int rb = a >> 1, kk = a & 1;
      glds16(Wg + (size_t)(n0 + rb * 16 + txl) * K + k0 + kk * 32 + 8 * q, sW + a * 512);
    }
    __syncthreads();  // drains vmcnt (loads landed in LDS)

#pragma unroll
    for (int kk = 0; kk < 2; kk++) {
      short8 af[TM], al[TM], wf[4];
#pragma unroll
      for (int i = 0; i < TM; i++) {
        const int rb = (w >> 1) * TM + i;
        af[i] = *(const short8*)&sA[(rb * 2 + kk) * 512 + lane * 8];
        if (SPLIT) al[i] = *(const short8*)&sL[(rb * 2 + kk) * 512 + lane * 8];
      }
#pragma unroll
      for (int j = 0; j < 4; j++) {
        const int rb = (w & 1) * 4 + j;
        wf[j] = *(const short8*)&sW[(rb * 2 + kk) * 512 + lane * 8];
      }
#pragma unroll
      for (int i = 0; i < TM; i++)
#pragma unroll
        for (int j = 0; j < 4; j++) {
          acc[i][j] = __builtin_amdgcn_mfma_f32_16x16x32_bf16(af[i], wf[j], acc[i][j], 0, 0, 0);
          if (SPLIT)
            acc[i][j] = __builtin_amdgcn_mfma_f32_16x16x32_bf16(al[i], wf[j], acc[i][j], 0, 0, 0);
        }
    }
  }

#pragma unroll
  for (int j = 0; j < 4; j++) {
    const int col = n0 + wc + 16 * j + txl;
    const float bj = bias[col];
    const float sc = (col < scale_limit) ? 0.125f : 1.0f;
#pragma unroll
    for (int i = 0; i < TM; i++) {
      const int rbase = m0 + wr + 16 * i + 4 * q;
#pragma unroll
      for (int r = 0; r < 4; r++) {
        const float v = (acc[i][j][r] + bj) * sc;
        if (BF16OUT) ((unsigned short*)Cout)[(size_t)(rbase + r) * N + col] = f2bf(v);
        else         ((float*)Cout)[(size_t)(rbase + r) * N + col] = v;
      }
    }
  }
}

// fused in-projections -> bf16 qkv/hkv (q columns pre-scaled by 0.125)
__global__ __launch_bounds__(256, 2) void gemm_inproj(
    const unsigned short* __restrict__ ghi, const unsigned short* __restrict__ glo,
    const unsigned short* __restrict__ wgi, const float* __restrict__ bgi,
    const unsigned short* __restrict__ hhi, const unsigned short* __restrict__ hlo,
    const unsigned short* __restrict__ whi, const float* __restrict__ bhi,
    unsigned short* __restrict__ qkv, unsigned short* __restrict__ hkv)
{
  __shared__ __align__(16) unsigned short sm[24576];  // 3 x 8192 shorts = 48 KB
  const int bx = blockIdx.x;
  const int m0 = blockIdx.y * 128;
  if (bx < 24)
    gemm_core2<4, true, true>(ghi, glo, wgi, bgi, 3072, 1024, m0, bx * 128, 1024,
                              qkv, sm, sm + 8192, sm + 16384);
  else
    gemm_core2<4, true, true>(hhi, hlo, whi, bhi, 2048, 1024, m0, (bx - 24) * 128, 0,
                              hkv, sm, sm + 8192, sm + 16384);
}

// fused out-projections: 64-row tiles (512 blocks = 2/CU), plain bf16
__global__ __launch_bounds__(256, 2) void gemm_outproj(
    const unsigned short* __restrict__ attnb,
    const unsigned short* __restrict__ wgo, const float* __restrict__ bgo,
    const unsigned short* __restrict__ who, const float* __restrict__ bho,
    float* __restrict__ out)
{
  __shared__ __align__(16) unsigned short sm[12288];  // 4096 + 8192 shorts = 24 KB
  const int m0 = blockIdx.y * 64;
  const unsigned short* Wp = (m0 < 2048) ? wgo : who;
  const float* bp = (m0 < 2048) ? bgo : bho;
  gemm_core2<2, false, false>(attnb, attnb, Wp, bp, 1024, 1024, m0, blockIdx.x * 128, 0,
                              out, sm, sm, sm + 4096);
}

// ---------------- MFMA dual-stream attention, split-s partials ----------------
// K/Q staged fragment-major via global_load_lds; V keeps transposed VGPR staging.
// KV region time-multiplexed: K-phase = 16 frag tiles x 512; V-phase = 2 x [64][72].
__global__ __launch_bounds__(256, 4) void attn_mfma(
    const unsigned short* __restrict__ qkv, const unsigned short* __restrict__ hkv,
    float* __restrict__ Opart, float* __restrict__ lpart)
{
  __shared__ __align__(16) unsigned short smem[18432];  // 36 KB -> 4 blocks/CU
  unsigned short* KV = smem;          // 9216 shorts
  unsigned short* PC = smem + 9216;   // 8 x 1152 shorts
  unsigned short* QS = smem + 9216;   // overlay: 8 tiles x 512 (pre-loop only)

  const int tid = threadIdx.x;
  const int w = tid >> 6;
  const int lane = tid & 63;
  const int txl = lane & 15, q = lane >> 4;
  const int t0 = blockIdx.x * 64;
  const int bh = blockIdx.y;
  const int z = blockIdx.z;
  const int b = bh >> 4;
  const int head = bh & 15;
  const int hoff = head * 64;

  // ---- stage Q fragment-major via glds (pre-scaled bf16 from inproj) ----
#pragma unroll
  for (int kk = 0; kk < 2; kk++)
    glds16(qkv + ((size_t)(t0 + 16 * w + txl) * 2 + b) * 3072 + hoff + 32 * kk + 8 * q,
           QS + (w * 2 + kk) * 512);
  __syncthreads();
  const short8 aq0 = *(const short8*)&QS[(w * 2 + 0) * 512 + lane * 8];
  const short8 aq1 = *(const short8*)&QS[(w * 2 + 1) * 512 + lane * 8];
  __syncthreads();  // all aq reads done before PC overwrites QS overlay

  f32x4 Og[4], Oh[4];
  float l_g[4], l_h[4];
#pragma unroll
  for (int i = 0; i < 4; i++) {
    Og[i] = (f32x4){0.f, 0.f, 0.f, 0.f};
    Oh[i] = (f32x4){0.f, 0.f, 0.f, 0.f};
    l_g[i] = 0.f; l_h[i] = 0.f;
  }

  unsigned short* pcg = PC + (w * 2 + 0) * 1152;
  unsigned short* pch = PC + (w * 2 + 1) * 1152;

  const int s_begin = z * (T_SEQ / 2);
  const int s_end = s_begin + (T_SEQ / 2);
  for (int s0 = s_begin; s0 < s_end; s0 += 64) {
    __syncthreads();  // PV reads of previous V done
    // ---- stage K fragment-major: 16 tiles, 4 glds per wave ----
#pragma unroll
    for (int t = 0; t < 4; t++) {
      const int idx = w * 4 + t;          // 0..7 = g stream, 8..15 = h stream
      const int tile = idx & 7;
      const int nt = tile >> 1, kk = tile & 1;
      const unsigned short* gp;
      if (idx < 8)
        gp = qkv + ((size_t)(s0 + 16 * nt + txl) * 2 + b) * 3072 + 1024 + hoff + 32 * kk + 8 * q;
      else
        gp = hkv + ((size_t)(s0 + 16 * nt + txl) * 2 + b) * 2048 + hoff + 32 * kk + 8 * q;
      glds16(gp, KV + idx * 512);
    }
    __syncthreads();

    // ---- dual score GEMMs (linear conflict-free frag reads) ----
    f32x4 Sg[4], Sh[4];
    const f32x4 zz = (f32x4){0.f, 0.f, 0.f, 0.f};
#pragma unroll
    for (int nt = 0; nt < 4; nt++) {
      const short8 bg0 = *(const short8*)&KV[(nt * 2 + 0) * 512 + lane * 8];
      const short8 bg1 = *(const short8*)&KV[(nt * 2 + 1) * 512 + lane * 8];
      const short8 bh0 = *(const short8*)&KV[(8 + nt * 2 + 0) * 512 + lane * 8];
      const short8 bh1 = *(const short8*)&KV[(8 + nt * 2 + 1) * 512 + lane * 8];
      f32x4 ag = __builtin_amdgcn_mfma_f32_16x16x32_bf16(aq0, bg0, zz, 0, 0, 0);
      ag = __builtin_amdgcn_mfma_f32_16x16x32_bf16(aq1, bg1, ag, 0, 0, 0);
      f32x4 ah = __builtin_amdgcn_mfma_f32_16x16x32_bf16(aq0, bh0, zz, 0, 0, 0);
      ah = __builtin_amdgcn_mfma_f32_16x16x32_bf16(aq1, bh1, ah, 0, 0, 0);
      Sg[nt] = ag; Sh[nt] = ah;
    }

    // ---- gumbel noise on h scores ----
#pragma unroll
    for (int nt = 0; nt < 4; nt++)
#pragma unroll
      for (int r = 0; r < 4; r++) {
        const uint32_t trow = (uint32_t)(t0 + 16 * w + 4 * q + r);
        const uint32_t scol_ = (uint32_t)(s0 + 16 * nt + txl);
        Sh[nt][r] += gumbel_noise(((uint32_t)bh << 20) | (trow << 10) | scol_);
      }

    // ---- exp (no max-sub), partial l, pack P col-major (wave-private) ----
#pragma unroll
    for (int nt = 0; nt < 4; nt++) {
      float eg[4], eh[4];
#pragma unroll
      for (int r = 0; r < 4; r++) {
        eg[r] = __expf(Sg[nt][r]); l_g[r] += eg[r];
        eh[r] = __expf(Sh[nt][r]); l_h[r] += eh[r];
      }
      const int sbase = (16 * nt + txl) * 18 + 4 * q;
      *(uint32_t*)&pcg[sbase]     = (uint32_t)f2bf(eg[0]) | ((uint32_t)f2bf(eg[1]) << 16);
      *(uint32_t*)&pcg[sbase + 2] = (uint32_t)f2bf(eg[2]) | ((uint32_t)f2bf(eg[3]) << 16);
      *(uint32_t*)&pch[sbase]     = (uint32_t)f2bf(eh[0]) | ((uint32_t)f2bf(eh[1]) << 16);
      *(uint32_t*)&pch[sbase + 2] = (uint32_t)f2bf(eh[2]) | ((uint32_t)f2bf(eh[3]) << 16);
    }

    __syncthreads();  // K frag reads done before V overwrites KV
    // ---- stage V transposed [d][s], stride-72 (proven R6 path) ----
    {
      const int dd = tid >> 2;
      const int sseg = (tid & 3) * 16;
      ushort8v vg[2], vh[2];
#pragma unroll
      for (int p = 0; p < 2; p++)
#pragma unroll
        for (int m = 0; m < 8; m++) {
          const int s = sseg + 8 * p + m;
          const size_t grow = (size_t)(s0 + s) * 2 + b;
          vg[p][m] = qkv[grow * 3072 + 2048 + hoff + dd];
          vh[p][m] = hkv[grow * 2048 + 1024 + hoff + dd];
        }
#pragma unroll
      for (int p = 0; p < 2; p++) {
        *(ushort8v*)&KV[dd * 72 + sseg + 8 * p]        = vg[p];
        *(ushort8v*)&KV[4608 + dd * 72 + sseg + 8 * p] = vh[p];
      }
    }
    __syncthreads();

    // ---- PV: O += P @ V ----
#pragma unroll
    for (int c = 0; c < 2; c++) {
      short8 apg, aph;
#pragma unroll
      for (int j = 0; j < 8; j++) {
        apg[j] = (short)pcg[(32 * c + 8 * q + j) * 18 + txl];
        aph[j] = (short)pch[(32 * c + 8 * q + j) * 18 + txl];
      }
#pragma unroll
      for (int nt = 0; nt < 4; nt++) {
        const int drow = (16 * nt + txl) * 72;
        const short8 bvg = *(const short8*)&KV[drow + 32 * c + 8 * q];
        const short8 bvh = *(const short8*)&KV[4608 + drow + 32 * c + 8 * q];
        Og[nt] = __builtin_amdgcn_mfma_f32_16x16x32_bf16(apg, bvg, Og[nt], 0, 0, 0);
        Oh[nt] = __builtin_amdgcn_mfma_f32_16x16x32_bf16(aph, bvh, Oh[nt], 0, 0, 0);
      }
    }
  }

  // ---- epilogue: reduce l once, write unnormalized fp32 partials ----
  float* opg = Opart + ((size_t)(z * 2 + 0) * 2048) * 1024;
  float* oph = Opart + ((size_t)(z * 2 + 1) * 2048) * 1024;
  float* lpg = lpart + (size_t)(z * 2 + 0) * 2048 * 16;
  float* lph = lpart + (size_t)(z * 2 + 1) * 2048 * 16;
#pragma unroll
  for (int r = 0; r < 4; r++) {
    float lg = l_g[r], lh = l_h[r];
    lg += __shfl_xor(lg, 1); lg += __shfl_xor(lg, 2);
    lg += __shfl_xor(lg, 4); lg += __shfl_xor(lg, 8);
    lh += __shfl_xor(lh, 1); lh += __shfl_xor(lh, 2);
    lh += __shfl_xor(lh, 4); lh += __shfl_xor(lh, 8);
    const int row = (t0 + 16 * w + 4 * q + r) * 2 + b;
    if (txl == 0) {
      lpg[row * 16 + head] = lg;
      lph[row * 16 + head] = lh;
    }
    const size_t base = (size_t)row * 1024 + hoff;
#pragma unroll
    for (int nt = 0; nt < 4; nt++) {
      opg[base + 16 * nt + txl] = Og[nt][r];
      oph[base + 16 * nt + txl] = Oh[nt][r];
    }
  }
}

// ---------------- merge split-s partials -> bf16 attnb ----------------
__global__ __launch_bounds__(256) void merge_attn(
    const float* __restrict__ Opart, const float* __restrict__ lpart,
    unsigned short* __restrict__ attnb)
{
  const int idx = blockIdx.x * 256 + threadIdx.x;
  const int st = idx >> 19;
  const int i = idx & 0x7FFFF;
  const int row = i >> 8;
  const int colq = i & 255;
  const int head = colq >> 4;
  const float4 o0 = *(const float4*)&Opart[((size_t)(0 + st) * 2048 + row) * 1024 + colq * 4];
  const float4 o1 = *(const float4*)&Opart[((size_t)(2 + st) * 2048 + row) * 1024 + colq * 4];
  const float l0 = lpart[(size_t)(0 + st) * 32768 + row * 16 + head];
  const float l1 = lpart[(size_t)(2 + st) * 32768 + row * 16 + head];
  const float inv = 1.0f / (l0 + l1);
  ushort4v u = {f2bf((o0.x + o1.x) * inv), f2bf((o0.y + o1.y) * inv),
                f2bf((o0.z + o1.z) * inv), f2bf((o0.w + o1.w) * inv)};
  *(ushort4v*)&attnb[((size_t)st * 2048 + row) * 1024 + colq * 4] = u;
}

extern "C" void kernel_launch(void* const* d_in, const int* in_sizes, int n_in,
                              void* d_out, int out_size, void* d_ws, size_t ws_size,
                              hipStream_t stream) {
  const float* g       = (const float*)d_in[0];
  const float* h       = (const float*)d_in[1];
  const float* g_in_w  = (const float*)d_in[2];
  const float* g_in_b  = (const float*)d_in[3];
  const float* h_in_w  = (const float*)d_in[4];
  const float* h_in_b  = (const float*)d_in[5];
  const float* g_out_w = (const float*)d_in[6];
  const float* g_out_b = (const float*)d_in[7];
  const float* h_out_w = (const float*)d_in[8];
  const float* h_out_b = (const float*)d_in[9];
  float* out = (float*)d_out;

  unsigned short* ws = (unsigned short*)d_ws;
  // persistent region
  unsigned short* qkv   = ws;                        // [2048][3072] bf16
  unsigned short* hkv   = qkv + (size_t)2048*3072;   // [2048][2048]
  unsigned short* attnb = hkv + (size_t)2048*2048;   // [4096][1024]
  unsigned short* wgo   = attnb + (size_t)4096*1024; // [1024][1024]
  unsigned short* who   = wgo + (size_t)1024*1024;   // [1024][1024]
  // scratch: conversion buffers (dead after inproj) overlaid with attn partials
  unsigned short* scratch = who + (size_t)1024*1024;
  unsigned short* ghi = scratch;
  unsigned short* glo = ghi + (size_t)2048*1024;
  unsigned short* hhi = glo + (size_t)2048*1024;
  unsigned short* hlo = hhi + (size_t)2048*1024;
  unsigned short* wgi = hlo + (size_t)2048*1024;     // [3072][1024]
  unsigned short* whi = wgi + (size_t)3072*1024;     // [2048][1024]
  float* Opart = (float*)scratch;                    // 4 planes x [2048][1024] fp32
  float* lpart = Opart + (size_t)4*2048*1024;        // 4 planes x [2048][16]

  convert_pre<<<1024, 256, 0, stream>>>(g, h, g_in_w, h_in_w, g_out_w, h_out_w,
                                        ghi, glo, hhi, hlo, wgi, whi, wgo, who);
  gemm_inproj<<<dim3(40, 16), 256, 0, stream>>>(
      ghi, glo, wgi, g_in_b, hhi, hlo, whi, h_in_b, qkv, hkv);
  attn_mfma<<<dim3(T_SEQ / 64, 32, 2), 256, 0, stream>>>(qkv, hkv, Opart, lpart);
  merge_attn<<<4096, 256, 0, stream>>>(Opart, lpart, attnb);
  gemm_outproj<<<dim3(8, 64), 256, 0, stream>>>(
      attnb, wgo, g_out_b, who, h_out_b, out);
}

// Round 8
// 285.375 us; speedup vs baseline: 1.1948x; 1.1948x over previous
//
#include <hip/hip_runtime.h>
#include <stdint.h>

#define T_SEQ 1024

typedef __attribute__((ext_vector_type(8))) short short8;
typedef __attribute__((ext_vector_type(4))) float f32x4;
typedef __attribute__((ext_vector_type(4))) unsigned short ushort4v;
typedef __attribute__((ext_vector_type(8))) unsigned short ushort8v;

__device__ __forceinline__ unsigned short f2bf(float f) {
  union { float f; uint32_t u; } v; v.f = f;
  return (unsigned short)((v.u + 0x7fffu + ((v.u >> 16) & 1u)) >> 16);
}
__device__ __forceinline__ float bf2f(unsigned short u) {
  union { uint32_t u; float f; } v; v.u = ((uint32_t)u) << 16;
  return v.f;
}

// ---------------- threefry2x32, JAX partitionable mode ----------------
__device__ __forceinline__ uint32_t tf_bits(uint32_t flat) {
  const uint32_t ks1 = 42u;
  const uint32_t ks2 = 0x1BD11BDAu ^ 42u;
  uint32_t x0 = 0u;
  uint32_t x1 = flat + ks1;
#define TFR(r) { x0 += x1; x1 = (x1 << (r)) | (x1 >> (32 - (r))); x1 ^= x0; }
  TFR(13) TFR(15) TFR(26) TFR(6)
  x0 += ks1; x1 += ks2 + 1u;
  TFR(17) TFR(29) TFR(16) TFR(24)
  x0 += ks2; x1 += 2u;
  TFR(13) TFR(15) TFR(26) TFR(6)
  x1 += ks1 + 3u;
  TFR(17) TFR(29) TFR(16) TFR(24)
  x0 += ks1; x1 += ks2 + 4u;
  TFR(13) TFR(15) TFR(26) TFR(6)
  x0 += ks2; x1 += 5u;
#undef TFR
  return x0 ^ x1;
}

__device__ __forceinline__ float gumbel_noise(uint32_t flat) {
  const uint32_t bits = tf_bits(flat);
  const float u = __uint_as_float((bits >> 9) | 0x3f800000u) - 1.0f;
  return -__logf(-__logf(u + 1e-20f) + 1e-20f);
}

// ---------------- pre-conversion pass: fp32 -> bf16 (plain, no split) ----------------
__global__ __launch_bounds__(256) void convert_pre(
    const float* __restrict__ g, const float* __restrict__ h,
    const float* __restrict__ wgi_f, const float* __restrict__ whi_f,
    const float* __restrict__ wgo_f, const float* __restrict__ who_f,
    unsigned short* __restrict__ gbf, unsigned short* __restrict__ hbf,
    unsigned short* __restrict__ wgi, unsigned short* __restrict__ whi,
    unsigned short* __restrict__ wgo, unsigned short* __restrict__ who)
{
  const int64_t Q_SPLIT = 1048576;              // (g 2M + h 2M) / 4
  const int64_t Q_TOTAL = Q_SPLIT + 1835008;    // + weights 7M / 4
  for (int64_t qd = (int64_t)blockIdx.x * 256 + threadIdx.x; qd < Q_TOTAL;
       qd += (int64_t)gridDim.x * 256) {
    if (qd < Q_SPLIT) {
      const int which = qd >= 524288;
      const int64_t e = (qd - (which ? 524288 : 0)) * 4;
      const float4 v = *(const float4*)((which ? h : g) + e);
      ushort4v u = {f2bf(v.x), f2bf(v.y), f2bf(v.z), f2bf(v.w)};
      *(ushort4v*)((which ? hbf : gbf) + e) = u;
    } else {
      int64_t off = qd - Q_SPLIT;
      const float* src; unsigned short* dst;
      if (off < 786432)                 { src = wgi_f; dst = wgi; }
      else if (off < 1310720)           { off -= 786432;  src = whi_f; dst = whi; }
      else if (off < 1572864)           { off -= 1310720; src = wgo_f; dst = wgo; }
      else                              { off -= 1572864; src = who_f; dst = who; }
      const int64_t e = off * 4;
      const float4 v = *(const float4*)(src + e);
      ushort4v u = {f2bf(v.x), f2bf(v.y), f2bf(v.z), f2bf(v.w)};
      *(ushort4v*)(dst + e) = u;
    }
  }
}

// ---------------- plain bf16 MFMA GEMM: C = A @ W^T + bias ----------------
// Tile (TM*32) rows x 128 cols, BK=64, 256 threads = 4 waves (2x2); wave tile (TM*16)x64.
// VGPR->LDS staging, stride 72 shorts -> 2-way-free b128 frag reads (proven R6 path).
template<int TM, bool BF16OUT>
__device__ __forceinline__ void gemm_plain_core(
    const unsigned short* __restrict__ Ab, const unsigned short* __restrict__ Wb,
    const float* __restrict__ bias, int N, int K, int m0, int n0,
    int scale_limit, void* Cout, unsigned short* sA, unsigned short* sW)
{
  const int tid = threadIdx.x;
  const int w = tid >> 6;
  const int lane = tid & 63;
  const int txl = lane & 15, q = lane >> 4;
  const int wr = (w >> 1) * (TM * 16);
  const int wc = (w & 1) << 6;
  const int TPR = 8 / TM;                    // threads per A row
  const int arow = tid / TPR;
  const int acol = (tid % TPR) * (8 * TM);   // shorts
  const int wrow = tid >> 1;
  const int wcol = (tid & 1) << 5;

  f32x4 acc[TM][4];
#pragma unroll
  for (int i = 0; i < TM; i++)
#pragma unroll
    for (int j = 0; j < 4; j++) acc[i][j] = (f32x4){0.f, 0.f, 0.f, 0.f};

  for (int k0 = 0; k0 < K; k0 += 64) {
    const unsigned short* Ap = Ab + (size_t)(m0 + arow) * K + k0 + acol;
    const unsigned short* Wp = Wb + (size_t)(n0 + wrow) * K + k0 + wcol;
    ushort8v a8[TM], w8[4];
#pragma unroll
    for (int e = 0; e < TM; e++) a8[e] = *(const ushort8v*)(Ap + 8 * e);
#pragma unroll
    for (int e = 0; e < 4; e++)  w8[e] = *(const ushort8v*)(Wp + 8 * e);
    __syncthreads();  // previous iter's frag reads complete
#pragma unroll
    for (int e = 0; e < TM; e++) *(ushort8v*)&sA[arow * 72 + acol + 8 * e] = a8[e];
#pragma unroll
    for (int e = 0; e < 4; e++)  *(ushort8v*)&sW[wrow * 72 + wcol + 8 * e] = w8[e];
    __syncthreads();
#pragma unroll
    for (int kk = 0; kk < 2; kk++) {
      short8 af[TM], wf[4];
#pragma unroll
      for (int i = 0; i < TM; i++)
        af[i] = *(const short8*)&sA[(wr + 16 * i + txl) * 72 + 32 * kk + 8 * q];
#pragma unroll
      for (int j = 0; j < 4; j++)
        wf[j] = *(const short8*)&sW[(wc + 16 * j + txl) * 72 + 32 * kk + 8 * q];
#pragma unroll
      for (int i = 0; i < TM; i++)
#pragma unroll
        for (int j = 0; j < 4; j++)
          acc[i][j] = __builtin_amdgcn_mfma_f32_16x16x32_bf16(af[i], wf[j], acc[i][j], 0, 0, 0);
    }
  }

#pragma unroll
  for (int j = 0; j < 4; j++) {
    const int col = n0 + wc + 16 * j + txl;
    const float bj = bias[col];
    const float sc = (col < scale_limit) ? 0.125f : 1.0f;
#pragma unroll
    for (int i = 0; i < TM; i++) {
      const int rbase = m0 + wr + 16 * i + 4 * q;
#pragma unroll
      for (int r = 0; r < 4; r++) {
        const float v = (acc[i][j][r] + bj) * sc;
        if (BF16OUT) ((unsigned short*)Cout)[(size_t)(rbase + r) * N + col] = f2bf(v);
        else         ((float*)Cout)[(size_t)(rbase + r) * N + col] = v;
      }
    }
  }
}

// fused in-projections -> bf16 qkv/hkv (q columns pre-scaled by 0.125); 36 KB LDS -> 4/CU
__global__ __launch_bounds__(256, 4) void gemm_inproj(
    const unsigned short* __restrict__ gbf, const unsigned short* __restrict__ wgi,
    const float* __restrict__ bgi,
    const unsigned short* __restrict__ hbf, const unsigned short* __restrict__ whi,
    const float* __restrict__ bhi,
    unsigned short* __restrict__ qkv, unsigned short* __restrict__ hkv)
{
  __shared__ __align__(16) unsigned short sm[18432];  // 2 x 9216 shorts = 36 KB
  const int bx = blockIdx.x;
  const int m0 = blockIdx.y * 128;
  if (bx < 24)
    gemm_plain_core<4, true>(gbf, wgi, bgi, 3072, 1024, m0, bx * 128, 1024,
                             qkv, sm, sm + 9216);
  else
    gemm_plain_core<4, true>(hbf, whi, bhi, 2048, 1024, m0, (bx - 24) * 128, 0,
                             hkv, sm, sm + 9216);
}

// fused out-projections: 64-row tiles (512 blocks = 2/CU), fp32 result
__global__ __launch_bounds__(256, 2) void gemm_outproj(
    const unsigned short* __restrict__ attnb,
    const unsigned short* __restrict__ wgo, const float* __restrict__ bgo,
    const unsigned short* __restrict__ who, const float* __restrict__ bho,
    float* __restrict__ out)
{
  __shared__ __align__(16) unsigned short sm[13824];  // 4608 + 9216 shorts = 27.6 KB
  const int m0 = blockIdx.y * 64;
  const unsigned short* Wp = (m0 < 2048) ? wgo : who;
  const float* bp = (m0 < 2048) ? bgo : bho;
  gemm_plain_core<2, false>(attnb, Wp, bp, 1024, 1024, m0, blockIdx.x * 128, 0,
                            out, sm, sm + 4608);
}

// ---------------- MFMA dual-stream attention, split-s partials (proven R6 kernel) ----------------
__global__ __launch_bounds__(256, 4) void attn_mfma(
    const unsigned short* __restrict__ qkv, const unsigned short* __restrict__ hkv,
    float* __restrict__ Opart, float* __restrict__ lpart)
{
  __shared__ __align__(16) unsigned short smem[18432];  // 36 KB -> 4 blocks/CU
  unsigned short* KV = smem;
  unsigned short* PC = smem + 9216;
  unsigned short* QS = smem + 9216;  // overlay, pre-loop only

  const int tid = threadIdx.x;
  const int w = tid >> 6;
  const int lane = tid & 63;
  const int txl = lane & 15, q = lane >> 4;
  const int t0 = blockIdx.x * 64;
  const int bh = blockIdx.y;
  const int z = blockIdx.z;
  const int b = bh >> 4;
  const int head = bh & 15;
  const int hoff = head * 64;
  const int sr = tid >> 2;
  const int sc = (tid & 3) << 4;

  // ---- stage Q (pre-scaled bf16 from inproj) ----
  {
    const size_t gq = ((size_t)(t0 + sr) * 2 + b) * 3072 + hoff + sc;
    *(ushort8v*)&QS[sr * 72 + sc]     = *(const ushort8v*)&qkv[gq];
    *(ushort8v*)&QS[sr * 72 + sc + 8] = *(const ushort8v*)&qkv[gq + 8];
  }
  __syncthreads();
  const short8 aq0 = *(const short8*)&QS[(16 * w + txl) * 72 + 8 * q];
  const short8 aq1 = *(const short8*)&QS[(16 * w + txl) * 72 + 32 + 8 * q];

  f32x4 Og[4], Oh[4];
  float l_g[4], l_h[4];
#pragma unroll
  for (int i = 0; i < 4; i++) {
    Og[i] = (f32x4){0.f, 0.f, 0.f, 0.f};
    Oh[i] = (f32x4){0.f, 0.f, 0.f, 0.f};
    l_g[i] = 0.f; l_h[i] = 0.f;
  }

  unsigned short* pcg = PC + (w * 2 + 0) * 1152;
  unsigned short* pch = PC + (w * 2 + 1) * 1152;

  const int s_begin = z * (T_SEQ / 2);
  const int s_end = s_begin + (T_SEQ / 2);
  for (int s0 = s_begin; s0 < s_end; s0 += 64) {
    __syncthreads();
    // ---- stage K, both streams, natural [s][72] ----
    {
      const size_t grow = (size_t)(s0 + sr) * 2 + b;
      const ushort8v kg0 = *(const ushort8v*)&qkv[grow * 3072 + 1024 + hoff + sc];
      const ushort8v kg1 = *(const ushort8v*)&qkv[grow * 3072 + 1024 + hoff + sc + 8];
      const ushort8v kh0 = *(const ushort8v*)&hkv[grow * 2048 + hoff + sc];
      const ushort8v kh1 = *(const ushort8v*)&hkv[grow * 2048 + hoff + sc + 8];
      *(ushort8v*)&KV[sr * 72 + sc]            = kg0;
      *(ushort8v*)&KV[sr * 72 + sc + 8]        = kg1;
      *(ushort8v*)&KV[4608 + sr * 72 + sc]     = kh0;
      *(ushort8v*)&KV[4608 + sr * 72 + sc + 8] = kh1;
    }
    __syncthreads();

    // ---- dual score GEMMs ----
    f32x4 Sg[4], Sh[4];
    const f32x4 zz = (f32x4){0.f, 0.f, 0.f, 0.f};
#pragma unroll
    for (int nt = 0; nt < 4; nt++) {
      const int srw = (16 * nt + txl) * 72;
      const short8 bg0 = *(const short8*)&KV[srw + 8 * q];
      const short8 bg1 = *(const short8*)&KV[srw + 32 + 8 * q];
      const short8 bh0 = *(const short8*)&KV[4608 + srw + 8 * q];
      const short8 bh1 = *(const short8*)&KV[4608 + srw + 32 + 8 * q];
      f32x4 ag = __builtin_amdgcn_mfma_f32_16x16x32_bf16(aq0, bg0, zz, 0, 0, 0);
      ag = __builtin_amdgcn_mfma_f32_16x16x32_bf16(aq1, bg1, ag, 0, 0, 0);
      f32x4 ah = __builtin_amdgcn_mfma_f32_16x16x32_bf16(aq0, bh0, zz, 0, 0, 0);
      ah = __builtin_amdgcn_mfma_f32_16x16x32_bf16(aq1, bh1, ah, 0, 0, 0);
      Sg[nt] = ag; Sh[nt] = ah;
    }

    // ---- gumbel noise on h scores ----
#pragma unroll
    for (int nt = 0; nt < 4; nt++)
#pragma unroll
      for (int r = 0; r < 4; r++) {
        const uint32_t trow = (uint32_t)(t0 + 16 * w + 4 * q + r);
        const uint32_t scol_ = (uint32_t)(s0 + 16 * nt + txl);
        Sh[nt][r] += gumbel_noise(((uint32_t)bh << 20) | (trow << 10) | scol_);
      }

    // ---- exp (no max-sub), partial l, pack P col-major (wave-private) ----
#pragma unroll
    for (int nt = 0; nt < 4; nt++) {
      float eg[4], eh[4];
#pragma unroll
      for (int r = 0; r < 4; r++) {
        eg[r] = __expf(Sg[nt][r]); l_g[r] += eg[r];
        eh[r] = __expf(Sh[nt][r]); l_h[r] += eh[r];
      }
      const int sbase = (16 * nt + txl) * 18 + 4 * q;
      *(uint32_t*)&pcg[sbase]     = (uint32_t)f2bf(eg[0]) | ((uint32_t)f2bf(eg[1]) << 16);
      *(uint32_t*)&pcg[sbase + 2] = (uint32_t)f2bf(eg[2]) | ((uint32_t)f2bf(eg[3]) << 16);
      *(uint32_t*)&pch[sbase]     = (uint32_t)f2bf(eh[0]) | ((uint32_t)f2bf(eh[1]) << 16);
      *(uint32_t*)&pch[sbase + 2] = (uint32_t)f2bf(eh[2]) | ((uint32_t)f2bf(eh[3]) << 16);
    }

    __syncthreads();
    // ---- stage V transposed [d][s], stride-72 ----
    {
      const int dd = tid >> 2;
      const int sseg = (tid & 3) * 16;
      ushort8v vg[2], vh[2];
#pragma unroll
      for (int p = 0; p < 2; p++)
#pragma unroll
        for (int m = 0; m < 8; m++) {
          const int s = sseg + 8 * p + m;
          const size_t grow = (size_t)(s0 + s) * 2 + b;
          vg[p][m] = qkv[grow * 3072 + 2048 + hoff + dd];
          vh[p][m] = hkv[grow * 2048 + 1024 + hoff + dd];
        }
#pragma unroll
      for (int p = 0; p < 2; p++) {
        *(ushort8v*)&KV[dd * 72 + sseg + 8 * p]        = vg[p];
        *(ushort8v*)&KV[4608 + dd * 72 + sseg + 8 * p] = vh[p];
      }
    }
    __syncthreads();

    // ---- PV: O += P @ V ----
#pragma unroll
    for (int c = 0; c < 2; c++) {
      short8 apg, aph;
#pragma unroll
      for (int j = 0; j < 8; j++) {
        apg[j] = (short)pcg[(32 * c + 8 * q + j) * 18 + txl];
        aph[j] = (short)pch[(32 * c + 8 * q + j) * 18 + txl];
      }
#pragma unroll
      for (int nt = 0; nt < 4; nt++) {
        const int drow = (16 * nt + txl) * 72;
        const short8 bvg = *(const short8*)&KV[drow + 32 * c + 8 * q];
        const short8 bvh = *(const short8*)&KV[4608 + drow + 32 * c + 8 * q];
        Og[nt] = __builtin_amdgcn_mfma_f32_16x16x32_bf16(apg, bvg, Og[nt], 0, 0, 0);
        Oh[nt] = __builtin_amdgcn_mfma_f32_16x16x32_bf16(aph, bvh, Oh[nt], 0, 0, 0);
      }
    }
  }

  // ---- epilogue: reduce l once, write unnormalized fp32 partials ----
  float* opg = Opart + ((size_t)(z * 2 + 0) * 2048) * 1024;
  float* oph = Opart + ((size_t)(z * 2 + 1) * 2048) * 1024;
  float* lpg = lpart + (size_t)(z * 2 + 0) * 2048 * 16;
  float* lph = lpart + (size_t)(z * 2 + 1) * 2048 * 16;
#pragma unroll
  for (int r = 0; r < 4; r++) {
    float lg = l_g[r], lh = l_h[r];
    lg += __shfl_xor(lg, 1); lg += __shfl_xor(lg, 2);
    lg += __shfl_xor(lg, 4); lg += __shfl_xor(lg, 8);
    lh += __shfl_xor(lh, 1); lh += __shfl_xor(lh, 2);
    lh += __shfl_xor(lh, 4); lh += __shfl_xor(lh, 8);
    const int row = (t0 + 16 * w + 4 * q + r) * 2 + b;
    if (txl == 0) {
      lpg[row * 16 + head] = lg;
      lph[row * 16 + head] = lh;
    }
    const size_t base = (size_t)row * 1024 + hoff;
#pragma unroll
    for (int nt = 0; nt < 4; nt++) {
      opg[base + 16 * nt + txl] = Og[nt][r];
      oph[base + 16 * nt + txl] = Oh[nt][r];
    }
  }
}

// ---------------- merge split-s partials -> bf16 attnb ----------------
__global__ __launch_bounds__(256) void merge_attn(
    const float* __restrict__ Opart, const float* __restrict__ lpart,
    unsigned short* __restrict__ attnb)
{
  const int idx = blockIdx.x * 256 + threadIdx.x;
  const int st = idx >> 19;
  const int i = idx & 0x7FFFF;
  const int row = i >> 8;
  const int colq = i & 255;
  const int head = colq >> 4;
  const float4 o0 = *(const float4*)&Opart[((size_t)(0 + st) * 2048 + row) * 1024 + colq * 4];
  const float4 o1 = *(const float4*)&Opart[((size_t)(2 + st) * 2048 + row) * 1024 + colq * 4];
  const float l0 = lpart[(size_t)(0 + st) * 32768 + row * 16 + head];
  const float l1 = lpart[(size_t)(2 + st) * 32768 + row * 16 + head];
  const float inv = 1.0f / (l0 + l1);
  ushort4v u = {f2bf((o0.x + o1.x) * inv), f2bf((o0.y + o1.y) * inv),
                f2bf((o0.z + o1.z) * inv), f2bf((o0.w + o1.w) * inv)};
  *(ushort4v*)&attnb[((size_t)st * 2048 + row) * 1024 + colq * 4] = u;
}

extern "C" void kernel_launch(void* const* d_in, const int* in_sizes, int n_in,
                              void* d_out, int out_size, void* d_ws, size_t ws_size,
                              hipStream_t stream) {
  const float* g       = (const float*)d_in[0];
  const float* h       = (const float*)d_in[1];
  const float* g_in_w  = (const float*)d_in[2];
  const float* g_in_b  = (const float*)d_in[3];
  const float* h_in_w  = (const float*)d_in[4];
  const float* h_in_b  = (const float*)d_in[5];
  const float* g_out_w = (const float*)d_in[6];
  const float* g_out_b = (const float*)d_in[7];
  const float* h_out_w = (const float*)d_in[8];
  const float* h_out_b = (const float*)d_in[9];
  float* out = (float*)d_out;

  unsigned short* ws = (unsigned short*)d_ws;
  // persistent region
  unsigned short* qkv   = ws;                        // [2048][3072] bf16
  unsigned short* hkv   = qkv + (size_t)2048*3072;   // [2048][2048]
  unsigned short* attnb = hkv + (size_t)2048*2048;   // [4096][1024]
  unsigned short* wgo   = attnb + (size_t)4096*1024; // [1024][1024]
  unsigned short* who   = wgo + (size_t)1024*1024;   // [1024][1024]
  // scratch: conversion buffers (dead after inproj) overlaid with attn partials
  unsigned short* scratch = who + (size_t)1024*1024;
  unsigned short* gbf = scratch;                     // [2048][1024]
  unsigned short* hbf = gbf + (size_t)2048*1024;     // [2048][1024]
  unsigned short* wgi = hbf + (size_t)2048*1024;     // [3072][1024]
  unsigned short* whi = wgi + (size_t)3072*1024;     // [2048][1024]
  float* Opart = (float*)scratch;                    // 4 planes x [2048][1024] fp32
  float* lpart = Opart + (size_t)4*2048*1024;        // 4 planes x [2048][16]

  convert_pre<<<1024, 256, 0, stream>>>(g, h, g_in_w, h_in_w, g_out_w, h_out_w,
                                        gbf, hbf, wgi, whi, wgo, who);
  gemm_inproj<<<dim3(40, 16), 256, 0, stream>>>(
      gbf, wgi, g_in_b, hbf, whi, h_in_b, qkv, hkv);
  attn_mfma<<<dim3(T_SEQ / 64, 32, 2), 256, 0, stream>>>(qkv, hkv, Opart, lpart);
  merge_attn<<<4096, 256, 0, stream>>>(Opart, lpart, attnb);
  gemm_outproj<<<dim3(8, 64), 256, 0, stream>>>(
      attnb, wgo, g_out_b, who, h_out_b, out);
}